// Round 3
// baseline (220.451 us; speedup 1.0000x reference)
//
#include <hip/hip_runtime.h>
#include <hip/hip_bf16.h>
#include <math.h>

#define NW 4096
#define NL 32
#define ND 256
#define ND2 512

typedef __attribute__((ext_vector_type(8))) short short8;
typedef __attribute__((ext_vector_type(4))) float floatx4;

__device__ inline float bfval(short s) {
  union { unsigned u; float f; } v;
  v.u = ((unsigned)(unsigned short)s) << 16;
  return v.f;
}

// ---------------------------------------------------------------------------
// ws layout:
//   wT    fp32 [3][256][256]            (chr conv w, [k][ci][co])
//   part  fp32 [512][64]
//   h     fp32 [1024]
//   Tb    bf16 [4 cotile][3 k][128 c][64 co]   (char conv tables)
//   u     bf16 [4098][512]  (guard rows at both ends)
//   Wb    bf16 [3][512 co][512 ci]      (sent conv w)
// ---------------------------------------------------------------------------

// prep: sent-w transpose->bf16, chr-w transpose, guard zero, word-emb gather
__global__ __launch_bounds__(256) void prep_kernel(
    const float* __restrict__ conv_sent_w, const float* __restrict__ conv_chr_w,
    const int* __restrict__ words, const float* __restrict__ word_emb,
    float* __restrict__ wT, __hip_bfloat16* __restrict__ Wb,
    short* __restrict__ u_base) {
  int b = blockIdx.x;
  int tid = threadIdx.x;
  if (b < 3072) {                         // sent w: 786432 elems
    int idx = b * 256 + tid;
    float v = conv_sent_w[idx];
    int co = idx / 1536;
    int rem = idx - co * 1536;
    int ci = rem / 3;
    int k = rem - ci * 3;
    Wb[k * 262144 + co * 512 + ci] = __float2bfloat16(v);
  } else if (b < 3840) {                  // chr w: 196608 elems
    int idx = (b - 3072) * 256 + tid;
    float v = conv_chr_w[idx];
    int co = idx / 768;
    int rem = idx - co * 768;
    int ci = rem / 3;
    int k = rem - ci * 3;
    wT[k * 65536 + ci * 256 + co] = v;
  } else if (b == 3840) {                 // guard rows
    u_base[tid] = 0;
    u_base[tid + 256] = 0;
    u_base[4097 * 512 + tid] = 0;
    u_base[4097 * 512 + tid + 256] = 0;
  } else {                                // word gather: 4096*256
    int idx = (b - 3841) * 256 + tid;
    int w = idx >> 8;
    int co = idx & 255;
    int wid = words[w];
    // u0 = u_base + 512
    u_base[512 + w * 512 + co] =
        ((short*)&((unsigned&)word_emb[wid * 256 + co]))[1];  // placeholder, replaced below
  }
}

// NOTE: trick above is fragile; do the gather properly in its own small kernel.
__global__ __launch_bounds__(256) void word_gather_kernel(
    const int* __restrict__ words, const float* __restrict__ word_emb,
    __hip_bfloat16* __restrict__ u0) {
  int idx = blockIdx.x * 256 + threadIdx.x;   // < 4096*256
  int w = idx >> 8;
  int co = idx & 255;
  int wid = words[w];
  u0[w * 512 + co] = __float2bfloat16(word_emb[wid * 256 + co]);
}

// T tables in bf16, layout [cotile][k][c][64co]
// grid 96: k = b>>5, c0 = (b&31)*4 ; 256 threads = co
__global__ __launch_bounds__(256) void table_kernel(
    const float* __restrict__ chr_emb, const float* __restrict__ wT,
    __hip_bfloat16* __restrict__ Tb) {
  __shared__ float s_e[4][256];
  int k = blockIdx.x >> 5;
  int c0 = (blockIdx.x & 31) * 4;
  int co = threadIdx.x;
#pragma unroll
  for (int j = 0; j < 4; ++j) s_e[j][co] = chr_emb[(c0 + j) * 256 + co];
  __syncthreads();
  const float* wk = wT + k * 65536;
  float a0 = 0.f, a1 = 0.f, a2 = 0.f, a3 = 0.f;
#pragma unroll 8
  for (int ci = 0; ci < 256; ++ci) {
    float w = wk[ci * 256 + co];
    a0 = fmaf(s_e[0][ci], w, a0);
    a1 = fmaf(s_e[1][ci], w, a1);
    a2 = fmaf(s_e[2][ci], w, a2);
    a3 = fmaf(s_e[3][ci], w, a3);
  }
  int base = ((co >> 6) * 3 + k) * 8192 + (co & 63);
  Tb[base + (c0 + 0) * 64] = __float2bfloat16(a0);
  Tb[base + (c0 + 1) * 64] = __float2bfloat16(a1);
  Tb[base + (c0 + 2) * 64] = __float2bfloat16(a2);
  Tb[base + (c0 + 3) * 64] = __float2bfloat16(a3);
}

// char path with LDS-staged bf16 tables.
// grid 256: cotile = b>>6 (64 cos), word chunk = (b&63)*64
__global__ __launch_bounds__(256) void char_word_kernel(
    const int* __restrict__ wic, const __hip_bfloat16* __restrict__ Tb,
    const float* __restrict__ bias, __hip_bfloat16* __restrict__ u0) {
  __shared__ short sT[3 * 128 * 64];   // 48 KB
  __shared__ int s_wic[64 * 32];       // 8 KB
  int ct = blockIdx.x >> 6;
  int w0 = (blockIdx.x & 63) * 64;
  int tid = threadIdx.x;
  {
    const uint4* src = (const uint4*)((const short*)Tb + ct * 24576);
    uint4* dst = (uint4*)sT;
#pragma unroll
    for (int i = 0; i < 12; ++i) dst[tid + i * 256] = src[tid + i * 256];
    const int4* wsrc = (const int4*)(wic + w0 * 32);
    int4* wdst = (int4*)s_wic;
    wdst[tid] = wsrc[tid];
    wdst[tid + 256] = wsrc[tid + 256];
  }
  __syncthreads();
  int co_l = tid & 63;
  int slot = tid >> 6;
  float bb = bias[ct * 64 + co_l];
  const short* T0 = sT;
  const short* T1 = sT + 8192;
  const short* T2 = sT + 16384;
  for (int wi = 0; wi < 16; ++wi) {
    int wl = slot * 16 + wi;
    const int* ch = s_wic + wl * 32;
    float m = -INFINITY;
#pragma unroll
    for (int t = 0; t < NL; ++t) {
      float s = bfval(T1[ch[t] * 64 + co_l]);
      if (t > 0) s += bfval(T0[ch[t - 1] * 64 + co_l]);
      if (t < NL - 1) s += bfval(T2[ch[t + 1] * 64 + co_l]);
      m = fmaxf(m, s);
    }
    u0[(w0 + wl) * ND2 + ND + ct * 64 + co_l] = __float2bfloat16(m + bb);
  }
}

// Sentence conv GEMM: C[co][t] = sum_k sum_ci Wb[k][co][ci]*u[t+k-1][ci]
// Block tile 128co x 64t, 4 waves (2co x 2t), wave tile 64co x 32t = 4x2 frags.
// XOR-swizzled LDS (chunk ^= row&7) -> conflict-free b128; register prefetch
// pipeline hides L2 staging latency at 1 block/CU.
__global__ __launch_bounds__(256) void sent_conv_mfma(
    const __hip_bfloat16* __restrict__ u0,
    const __hip_bfloat16* __restrict__ Wb,
    float* __restrict__ partial) {
  __shared__ short As[128 * 64];   // 16 KB  [row co][64 K]
  __shared__ short Bs[64 * 64];    // 8 KB   [row t ][64 K]
  __shared__ float sm[2][128];
  const int tid = threadIdx.x;
  const int t0 = blockIdx.x * 64;
  const int co0 = blockIdx.y * 128;
  const int wave = tid >> 6, lane = tid & 63;
  const int wy = wave >> 1, wx = wave & 1;
  const int m = lane & 15, q = lane >> 4;

  floatx4 acc[4][2];
#pragma unroll
  for (int i = 0; i < 4; ++i)
#pragma unroll
    for (int j = 0; j < 2; ++j) acc[i][j] = (floatx4){0.f, 0.f, 0.f, 0.f};

  // Precompute swizzled LDS read offsets (constant across all steps)
  int aoff[2][4], boff[2][2];
#pragma unroll
  for (int kk = 0; kk < 2; ++kk) {
#pragma unroll
    for (int i = 0; i < 4; ++i) {
      int row = wy * 64 + i * 16 + m;
      aoff[kk][i] = row * 64 + (((kk * 4 + q) ^ (row & 7)) * 8);
    }
#pragma unroll
    for (int j = 0; j < 2; ++j) {
      int row = wx * 32 + j * 16 + m;
      boff[kk][j] = row * 64 + (((kk * 4 + q) ^ (row & 7)) * 8);
    }
  }

  const int sc = tid & 7, sr = tid >> 3;        // staging: chunk, row-base
  const int swc = (sc ^ (sr & 7)) * 8;          // swizzled chunk offset (shorts)
  const short* WbS = (const short*)Wb;
  const short* uS = (const short*)u0;

  uint4 pa[4], pb[2];
  // preload step 0
  {
    const short* WbK = WbS;                     // k=0
    const short* uK = uS + (t0 - 1) * 512;
#pragma unroll
    for (int ii = 0; ii < 4; ++ii)
      pa[ii] = *(const uint4*)(WbK + (co0 + sr + ii * 32) * 512 + sc * 8);
#pragma unroll
    for (int ii = 0; ii < 2; ++ii)
      pb[ii] = *(const uint4*)(uK + (sr + ii * 32) * 512 + sc * 8);
  }

  for (int s = 0; s < 24; ++s) {
    // commit prefetched tile to LDS
#pragma unroll
    for (int ii = 0; ii < 4; ++ii)
      *(uint4*)&As[(sr + ii * 32) * 64 + swc] = pa[ii];
#pragma unroll
    for (int ii = 0; ii < 2; ++ii)
      *(uint4*)&Bs[(sr + ii * 32) * 64 + swc] = pb[ii];
    __syncthreads();
    // prefetch next tile (global->reg, latency overlapped with MFMA below)
    if (s + 1 < 24) {
      int sn = s + 1;
      int k = sn >> 3, ci0 = (sn & 7) << 6;
      const short* WbK = WbS + k * 262144;
      const short* uK = uS + (t0 + k - 1) * 512;
#pragma unroll
      for (int ii = 0; ii < 4; ++ii)
        pa[ii] = *(const uint4*)(WbK + (co0 + sr + ii * 32) * 512 + ci0 + sc * 8);
#pragma unroll
      for (int ii = 0; ii < 2; ++ii)
        pb[ii] = *(const uint4*)(uK + (sr + ii * 32) * 512 + ci0 + sc * 8);
    }
#pragma unroll
    for (int kk = 0; kk < 2; ++kk) {
      short8 b0 = *(const short8*)&Bs[boff[kk][0]];
      short8 b1 = *(const short8*)&Bs[boff[kk][1]];
#pragma unroll
      for (int i = 0; i < 4; ++i) {
        short8 a = *(const short8*)&As[aoff[kk][i]];
        acc[i][0] = __builtin_amdgcn_mfma_f32_16x16x32_bf16(a, b0, acc[i][0], 0, 0, 0);
        acc[i][1] = __builtin_amdgcn_mfma_f32_16x16x32_bf16(a, b1, acc[i][1], 0, 0, 0);
      }
    }
    __syncthreads();
  }

  // epilogue: max over t (j frags + 16 t lanes)
#pragma unroll
  for (int i = 0; i < 4; ++i)
#pragma unroll
    for (int r = 0; r < 4; ++r) {
      float x = fmaxf(acc[i][0][r], acc[i][1][r]);
#pragma unroll
      for (int off = 1; off < 16; off <<= 1)
        x = fmaxf(x, __shfl_xor(x, off, 64));
      if (m == 0) sm[wx][wy * 64 + i * 16 + q * 4 + r] = x;
    }
  __syncthreads();
  if (tid < 128)
    partial[(co0 + tid) * 64 + blockIdx.x] = fmaxf(sm[0][tid], sm[1][tid]);
}

// fc1 with fused r-reduction: each block recomputes r[512] from partial, then
// 8 waves each compute one h output. grid 128 x 512 threads.
__global__ __launch_bounds__(512) void fc1_kernel(
    const float* __restrict__ partial, const float* __restrict__ bs,
    const float* __restrict__ w1, const float* __restrict__ b1,
    float* __restrict__ h) {
  __shared__ float s_r[512];
  int tid = threadIdx.x;
  {
    const float4* p = (const float4*)(partial + tid * 64);
    float mm = -INFINITY;
#pragma unroll
    for (int j = 0; j < 16; ++j) {
      float4 v = p[j];
      mm = fmaxf(mm, fmaxf(fmaxf(v.x, v.y), fmaxf(v.z, v.w)));
    }
    s_r[tid] = mm + bs[tid];
  }
  __syncthreads();
  int wave = tid >> 6, lane = tid & 63;
  int o = blockIdx.x * 8 + wave;
  const float4* wv = (const float4*)(w1 + o * 512 + lane * 8);
  const float4* rv = (const float4*)(s_r + lane * 8);
  float4 w0 = wv[0], w1v = wv[1];
  float4 r0 = rv[0], r1 = rv[1];
  float acc = w0.x * r0.x + w0.y * r0.y + w0.z * r0.z + w0.w * r0.w +
              w1v.x * r1.x + w1v.y * r1.y + w1v.z * r1.z + w1v.w * r1.w;
#pragma unroll
  for (int off = 32; off >= 1; off >>= 1) acc += __shfl_down(acc, off, 64);
  if (lane == 0) h[o] = tanhf(acc + b1[o]);
}

__global__ __launch_bounds__(128) void fc2_kernel(
    const float* __restrict__ h, const float* __restrict__ w2,
    const float* __restrict__ b2, float* __restrict__ out) {
  int tid = threadIdx.x;
  int o = tid >> 6;
  int lane = tid & 63;
  float acc = 0.f;
#pragma unroll
  for (int j = 0; j < 16; ++j)
    acc = fmaf(w2[o * 1024 + lane + j * 64], h[lane + j * 64], acc);
#pragma unroll
  for (int off = 32; off >= 1; off >>= 1) acc += __shfl_down(acc, off, 64);
  if (lane == 0) out[o] = acc + b2[o];
}

extern "C" void kernel_launch(void* const* d_in, const int* in_sizes, int n_in,
                              void* d_out, int out_size, void* d_ws, size_t ws_size,
                              hipStream_t stream) {
  const int*   words       = (const int*)d_in[0];
  const int*   wic         = (const int*)d_in[1];
  const float* word_emb    = (const float*)d_in[2];
  const float* chr_emb     = (const float*)d_in[3];
  const float* conv_chr_w  = (const float*)d_in[4];
  const float* conv_chr_b  = (const float*)d_in[5];
  const float* conv_sent_w = (const float*)d_in[6];
  const float* conv_sent_b = (const float*)d_in[7];
  const float* w1          = (const float*)d_in[8];
  const float* b1          = (const float*)d_in[9];
  const float* w2          = (const float*)d_in[10];
  const float* b2          = (const float*)d_in[11];
  float* out = (float*)d_out;

  float* ws    = (float*)d_ws;
  float* wT    = ws;                        // 196608 f
  float* part  = wT + 196608;               // 32768 f
  float* h_buf = part + 32768;              // 1024 f
  short* Tb    = (short*)(h_buf + 1024);    // 98304 bf16
  short* u_base = Tb + 98304;               // 4098*512 bf16
  __hip_bfloat16* u0 = (__hip_bfloat16*)(u_base + 512);
  __hip_bfloat16* Wb = (__hip_bfloat16*)(u_base + 4098 * 512);

  // prep (weights transpose + guards); word gather separate (clean bf16 cvt)
  prep_kernel<<<3841, 256, 0, stream>>>(conv_sent_w, conv_chr_w, words,
                                        word_emb, wT, Wb, u_base);
  word_gather_kernel<<<4096, 256, 0, stream>>>(words, word_emb, u0);
  table_kernel<<<96, 256, 0, stream>>>(chr_emb, wT, (__hip_bfloat16*)Tb);
  char_word_kernel<<<256, 256, 0, stream>>>(wic, (const __hip_bfloat16*)Tb,
                                            conv_chr_b, u0);
  sent_conv_mfma<<<dim3(64, 4), 256, 0, stream>>>(u0, Wb, part);
  fc1_kernel<<<128, 512, 0, stream>>>(part, conv_sent_b, w1, b1, h_buf);
  fc2_kernel<<<1, 128, 0, stream>>>(h_buf, w2, b2, out);
}

// Round 4
// 159.032 us; speedup vs baseline: 1.3862x; 1.3862x over previous
//
#include <hip/hip_runtime.h>
#include <hip/hip_bf16.h>
#include <math.h>

#define NW 4096
#define NL 32
#define ND 256
#define ND2 512

typedef __attribute__((ext_vector_type(8))) short short8;
typedef __attribute__((ext_vector_type(4))) float floatx4;

__device__ inline float bfval(short s) {
  union { unsigned u; float f; } v;
  v.u = ((unsigned)(unsigned short)s) << 16;
  return v.f;
}

// ---------------------------------------------------------------------------
// ws layout:
//   wT    fp32 [3][256][256]                 (chr conv w, [k][ci][co])
//   part  fp32 [512][64]
//   h     fp32 [1024]
//   Tb    bf16 [4 cotile][3 k][128 c][64 co] (char conv tables)
//   u     bf16 [4098][512]  (guard rows at both ends)
//   Wb    bf16 [3][512 co][512 ci]           (sent conv w)
// ---------------------------------------------------------------------------

// prep: sent-w transpose->bf16, chr-w transpose, guard zero. 3841 blocks.
__global__ __launch_bounds__(256) void prep_kernel(
    const float* __restrict__ conv_sent_w, const float* __restrict__ conv_chr_w,
    float* __restrict__ wT, __hip_bfloat16* __restrict__ Wb,
    short* __restrict__ u_base) {
  int b = blockIdx.x;
  int tid = threadIdx.x;
  if (b < 3072) {                         // sent w: 786432 elems
    int idx = b * 256 + tid;
    float v = conv_sent_w[idx];
    int co = idx / 1536;
    int rem = idx - co * 1536;
    int ci = rem / 3;
    int k = rem - ci * 3;
    Wb[k * 262144 + co * 512 + ci] = __float2bfloat16(v);
  } else if (b < 3840) {                  // chr w: 196608 elems
    int idx = (b - 3072) * 256 + tid;
    float v = conv_chr_w[idx];
    int co = idx / 768;
    int rem = idx - co * 768;
    int ci = rem / 3;
    int k = rem - ci * 3;
    wT[k * 65536 + ci * 256 + co] = v;
  } else {                                // guard rows (t=-1, t=4096)
    u_base[tid] = 0;
    u_base[tid + 256] = 0;
    u_base[4097 * 512 + tid] = 0;
    u_base[4097 * 512 + tid + 256] = 0;
  }
}

// T tables in bf16, layout [cotile][k][c][64co]
// grid 96: k = b>>5, c0 = (b&31)*4 ; 256 threads = co
__global__ __launch_bounds__(256) void table_kernel(
    const float* __restrict__ chr_emb, const float* __restrict__ wT,
    __hip_bfloat16* __restrict__ Tb) {
  __shared__ float s_e[4][256];
  int k = blockIdx.x >> 5;
  int c0 = (blockIdx.x & 31) * 4;
  int co = threadIdx.x;
#pragma unroll
  for (int j = 0; j < 4; ++j) s_e[j][co] = chr_emb[(c0 + j) * 256 + co];
  __syncthreads();
  const float* wk = wT + k * 65536;
  float a0 = 0.f, a1 = 0.f, a2 = 0.f, a3 = 0.f;
#pragma unroll 8
  for (int ci = 0; ci < 256; ++ci) {
    float w = wk[ci * 256 + co];
    a0 = fmaf(s_e[0][ci], w, a0);
    a1 = fmaf(s_e[1][ci], w, a1);
    a2 = fmaf(s_e[2][ci], w, a2);
    a3 = fmaf(s_e[3][ci], w, a3);
  }
  int base = ((co >> 6) * 3 + k) * 8192 + (co & 63);
  Tb[base + (c0 + 0) * 64] = __float2bfloat16(a0);
  Tb[base + (c0 + 1) * 64] = __float2bfloat16(a1);
  Tb[base + (c0 + 2) * 64] = __float2bfloat16(a2);
  Tb[base + (c0 + 3) * 64] = __float2bfloat16(a3);
}

// char path with LDS-staged bf16 tables + fused word-emb gather.
// grid 256: cotile = b>>6 (64 cos), word chunk = (b&63)*64
__global__ __launch_bounds__(256) void char_word_kernel(
    const int* __restrict__ words, const int* __restrict__ wic,
    const __hip_bfloat16* __restrict__ Tb, const float* __restrict__ word_emb,
    const float* __restrict__ bias, __hip_bfloat16* __restrict__ u0) {
  __shared__ short sT[3 * 128 * 64];   // 48 KB
  __shared__ int s_wic[64 * 32];       // 8 KB
  __shared__ int s_wid[64];
  int ct = blockIdx.x >> 6;
  int w0 = (blockIdx.x & 63) * 64;
  int tid = threadIdx.x;
  {
    const uint4* src = (const uint4*)((const short*)Tb + ct * 24576);
    uint4* dst = (uint4*)sT;
#pragma unroll
    for (int i = 0; i < 12; ++i) dst[tid + i * 256] = src[tid + i * 256];
    const int4* wsrc = (const int4*)(wic + w0 * 32);
    int4* wdst = (int4*)s_wic;
    wdst[tid] = wsrc[tid];
    wdst[tid + 256] = wsrc[tid + 256];
    if (tid < 64) s_wid[tid] = words[w0 + tid];
  }
  __syncthreads();
  int co_l = tid & 63;
  int slot = tid >> 6;
  float bb = bias[ct * 64 + co_l];
  const short* T0 = sT;
  const short* T1 = sT + 8192;
  const short* T2 = sT + 16384;
  for (int wi = 0; wi < 16; ++wi) {
    int wl = slot * 16 + wi;
    // word-emb gather for this co slice (coalesced 256B per word)
    u0[(w0 + wl) * ND2 + ct * 64 + co_l] =
        __float2bfloat16(word_emb[s_wid[wl] * ND + ct * 64 + co_l]);
    const int* ch = s_wic + wl * 32;
    float m = -INFINITY;
#pragma unroll
    for (int t = 0; t < NL; ++t) {
      float s = bfval(T1[ch[t] * 64 + co_l]);
      if (t > 0) s += bfval(T0[ch[t - 1] * 64 + co_l]);
      if (t < NL - 1) s += bfval(T2[ch[t + 1] * 64 + co_l]);
      m = fmaxf(m, s);
    }
    u0[(w0 + wl) * ND2 + ND + ct * 64 + co_l] = __float2bfloat16(m + bb);
  }
}

// Sentence conv GEMM: C[co][t] = sum_k sum_ci Wb[k][co][ci]*u[t+k-1][ci]
// R2 structure (64co x 64t, 512 blocks = 2/CU, simple synchronous staging)
// + R3's XOR swizzle (measured 0 bank conflicts). No register prefetch —
// implicit cross-block wave overlap (m114) hides the barrier drain.
__global__ __launch_bounds__(256, 2) void sent_conv_mfma(
    const __hip_bfloat16* __restrict__ u0,
    const __hip_bfloat16* __restrict__ Wb,
    float* __restrict__ partial) {
  __shared__ short As[64 * 64];   // 8 KB  [co row][64 K], 16B chunks XOR-swizzled
  __shared__ short Bs[64 * 64];   // 8 KB  [t row][64 K]
  __shared__ float sm[4][32];
  const int tid = threadIdx.x;
  const int t0 = blockIdx.x * 64;
  const int co0 = blockIdx.y * 64;
  const int wave = tid >> 6, lane = tid & 63;
  const int wy = wave >> 1, wx = wave & 1;
  const int m = lane & 15, q = lane >> 4;

  floatx4 acc[2][2];
#pragma unroll
  for (int i = 0; i < 2; ++i)
#pragma unroll
    for (int j = 0; j < 2; ++j) acc[i][j] = (floatx4){0.f, 0.f, 0.f, 0.f};

  // swizzled read offsets (constants, unrolled)
  int aoff[2][2], boff[2][2];
#pragma unroll
  for (int kk = 0; kk < 2; ++kk) {
#pragma unroll
    for (int i = 0; i < 2; ++i) {
      int row = wy * 32 + i * 16 + m;
      aoff[kk][i] = row * 64 + (((kk * 4 + q) ^ (row & 7)) * 8);
      row = wx * 32 + i * 16 + m;
      boff[kk][i] = row * 64 + (((kk * 4 + q) ^ (row & 7)) * 8);
    }
  }

  const int sc = tid & 7, sr = tid >> 3;   // staging: chunk, row (0..31)
  const int swc = (sc ^ (sr & 7)) * 8;     // swizzled chunk (row&7 == sr&7 for row=sr+32i)
  const short* WbS = (const short*)Wb;
  const short* uS = (const short*)u0;

  for (int s = 0; s < 24; ++s) {
    int k = s >> 3, ci0 = (s & 7) << 6;
    const short* WbK = WbS + k * 262144 + (co0 + sr) * 512 + ci0 + sc * 8;
    const short* uK = uS + (t0 + sr + k - 1) * 512 + ci0 + sc * 8;
    uint4 a0 = *(const uint4*)(WbK);
    uint4 a1 = *(const uint4*)(WbK + 32 * 512);
    uint4 b0 = *(const uint4*)(uK);
    uint4 b1 = *(const uint4*)(uK + 32 * 512);
    *(uint4*)&As[sr * 64 + swc] = a0;
    *(uint4*)&As[(sr + 32) * 64 + swc] = a1;
    *(uint4*)&Bs[sr * 64 + swc] = b0;
    *(uint4*)&Bs[(sr + 32) * 64 + swc] = b1;
    __syncthreads();
#pragma unroll
    for (int kk = 0; kk < 2; ++kk) {
      short8 av0 = *(const short8*)&As[aoff[kk][0]];
      short8 av1 = *(const short8*)&As[aoff[kk][1]];
      short8 bv0 = *(const short8*)&Bs[boff[kk][0]];
      short8 bv1 = *(const short8*)&Bs[boff[kk][1]];
      acc[0][0] = __builtin_amdgcn_mfma_f32_16x16x32_bf16(av0, bv0, acc[0][0], 0, 0, 0);
      acc[0][1] = __builtin_amdgcn_mfma_f32_16x16x32_bf16(av0, bv1, acc[0][1], 0, 0, 0);
      acc[1][0] = __builtin_amdgcn_mfma_f32_16x16x32_bf16(av1, bv0, acc[1][0], 0, 0, 0);
      acc[1][1] = __builtin_amdgcn_mfma_f32_16x16x32_bf16(av1, bv1, acc[1][1], 0, 0, 0);
    }
    __syncthreads();
  }

  // epilogue: max over t within block
  // acc[i][j] reg r: co = co0 + wy*32 + i*16 + q*4 + r
#pragma unroll
  for (int i = 0; i < 2; ++i)
#pragma unroll
    for (int r = 0; r < 4; ++r) {
      float x = fmaxf(acc[i][0][r], acc[i][1][r]);
#pragma unroll
      for (int off = 1; off < 16; off <<= 1)
        x = fmaxf(x, __shfl_xor(x, off, 64));
      if (m == 0) sm[wave][i * 16 + q * 4 + r] = x;
    }
  __syncthreads();
  if (tid < 64) {
    int whalf = tid >> 5;
    float v = fmaxf(sm[whalf * 2 + 0][tid & 31], sm[whalf * 2 + 1][tid & 31]);
    partial[(co0 + tid) * 64 + blockIdx.x] = v;
  }
}

// fc1 with fused r-reduction. grid 128 x 512 threads (8 waves -> 8 outputs).
__global__ __launch_bounds__(512) void fc1_kernel(
    const float* __restrict__ partial, const float* __restrict__ bs,
    const float* __restrict__ w1, const float* __restrict__ b1,
    float* __restrict__ h) {
  __shared__ float s_r[512];
  int tid = threadIdx.x;
  {
    const float4* p = (const float4*)(partial + tid * 64);
    float mm = -INFINITY;
#pragma unroll
    for (int j = 0; j < 16; ++j) {
      float4 v = p[j];
      mm = fmaxf(mm, fmaxf(fmaxf(v.x, v.y), fmaxf(v.z, v.w)));
    }
    s_r[tid] = mm + bs[tid];
  }
  __syncthreads();
  int wave = tid >> 6, lane = tid & 63;
  int o = blockIdx.x * 8 + wave;
  const float4* wv = (const float4*)(w1 + o * 512 + lane * 8);
  const float4* rv = (const float4*)(s_r + lane * 8);
  float4 w0 = wv[0], w1v = wv[1];
  float4 r0 = rv[0], r1 = rv[1];
  float acc = w0.x * r0.x + w0.y * r0.y + w0.z * r0.z + w0.w * r0.w +
              w1v.x * r1.x + w1v.y * r1.y + w1v.z * r1.z + w1v.w * r1.w;
#pragma unroll
  for (int off = 32; off >= 1; off >>= 1) acc += __shfl_down(acc, off, 64);
  if (lane == 0) h[o] = tanhf(acc + b1[o]);
}

__global__ __launch_bounds__(128) void fc2_kernel(
    const float* __restrict__ h, const float* __restrict__ w2,
    const float* __restrict__ b2, float* __restrict__ out) {
  int tid = threadIdx.x;
  int o = tid >> 6;
  int lane = tid & 63;
  float acc = 0.f;
#pragma unroll
  for (int j = 0; j < 16; ++j)
    acc = fmaf(w2[o * 1024 + lane + j * 64], h[lane + j * 64], acc);
#pragma unroll
  for (int off = 32; off >= 1; off >>= 1) acc += __shfl_down(acc, off, 64);
  if (lane == 0) out[o] = acc + b2[o];
}

extern "C" void kernel_launch(void* const* d_in, const int* in_sizes, int n_in,
                              void* d_out, int out_size, void* d_ws, size_t ws_size,
                              hipStream_t stream) {
  const int*   words       = (const int*)d_in[0];
  const int*   wic         = (const int*)d_in[1];
  const float* word_emb    = (const float*)d_in[2];
  const float* chr_emb     = (const float*)d_in[3];
  const float* conv_chr_w  = (const float*)d_in[4];
  const float* conv_chr_b  = (const float*)d_in[5];
  const float* conv_sent_w = (const float*)d_in[6];
  const float* conv_sent_b = (const float*)d_in[7];
  const float* w1          = (const float*)d_in[8];
  const float* b1          = (const float*)d_in[9];
  const float* w2          = (const float*)d_in[10];
  const float* b2          = (const float*)d_in[11];
  float* out = (float*)d_out;

  float* ws    = (float*)d_ws;
  float* wT    = ws;                        // 196608 f
  float* part  = wT + 196608;               // 32768 f
  float* h_buf = part + 32768;              // 1024 f
  short* Tb    = (short*)(h_buf + 1024);    // 98304 bf16
  short* u_base = Tb + 98304;               // 4098*512 bf16
  __hip_bfloat16* u0 = (__hip_bfloat16*)(u_base + 512);
  __hip_bfloat16* Wb = (__hip_bfloat16*)(u_base + 4098 * 512);

  prep_kernel<<<3841, 256, 0, stream>>>(conv_sent_w, conv_chr_w, wT, Wb, u_base);
  table_kernel<<<96, 256, 0, stream>>>(chr_emb, wT, (__hip_bfloat16*)Tb);
  char_word_kernel<<<256, 256, 0, stream>>>(words, wic, (const __hip_bfloat16*)Tb,
                                            word_emb, conv_chr_b, u0);
  sent_conv_mfma<<<dim3(64, 8), 256, 0, stream>>>(u0, Wb, part);
  fc1_kernel<<<128, 512, 0, stream>>>(part, conv_sent_b, w1, b1, h_buf);
  fc2_kernel<<<1, 128, 0, stream>>>(h_buf, w2, b2, out);
}